// Round 1
// baseline (626.562 us; speedup 1.0000x reference)
//
#include <hip/hip_runtime.h>
#include <hip/hip_bf16.h>

typedef _Float16 f16x2 __attribute__((ext_vector_type(2)));
typedef _Float16 f16x8 __attribute__((ext_vector_type(8)));

#define IN_DIM  32
#define EDGE_DIM 16
#define HDIM    64
#define OUT_DIM 6
#define BN_EPS  1e-5f

#if __has_builtin(__builtin_amdgcn_fdot2)
__device__ __forceinline__ float fdot2(f16x2 a, f16x2 b, float c) {
    return __builtin_amdgcn_fdot2(a, b, c, false);
}
#else
__device__ __forceinline__ float fdot2(f16x2 a, f16x2 b, float c) {
    return c + (float)a[0]*(float)b[0] + (float)a[1]*(float)b[1];
}
#endif

// ---------------- conversion kernels (one-time per call, tiny) ----------------

// We fp32 [3][16][4096] -> f16 transposed [3][4096][16]
__global__ void k_convert_we(const float* __restrict__ We, _Float16* __restrict__ WeT, int total) {
    int tid = blockIdx.x * 256 + threadIdx.x;
    if (tid >= total) return;
    int l = tid >> 16;
    int r = tid & 65535;
    int col = r >> 4, k = r & 15;
    WeT[tid] = (_Float16)We[l * 65536 + k * 4096 + col];
}

// edge_attr fp32 [E][16] -> f16x2 [E][8]
__global__ void k_convert_ea(const float* __restrict__ ea, f16x2* __restrict__ eaH, int total2) {
    int tid = blockIdx.x * 256 + threadIdx.x;
    if (tid >= total2) return;
    float2 v = ((const float2*)ea)[tid];
    f16x2 r; r[0] = (_Float16)v.x; r[1] = (_Float16)v.y;
    eaH[tid] = r;
}

__global__ void k_count(const int* __restrict__ idx, float* __restrict__ cnt, int n) {
    int tid = blockIdx.x * 256 + threadIdx.x;
    if (tid < n) atomicAdd(&cnt[idx[tid]], 1.0f);
}

// ---------------- node encoder: h = x @ Wx + bx ----------------
__global__ void k_encode(const float* __restrict__ x, const float* __restrict__ Wx,
                         const float* __restrict__ bx, float* __restrict__ h, int N) {
    int tid = blockIdx.x * 256 + threadIdx.x;      // N*16 threads, float4 over j
    int n = tid >> 4, jq = tid & 15;
    if (n >= N) return;
    const float4* W4 = (const float4*)Wx;
    float4 acc = ((const float4*)bx)[jq];
    const float4* xv = (const float4*)(x + (size_t)n * IN_DIM);
    #pragma unroll
    for (int k4 = 0; k4 < 8; ++k4) {
        float4 xk = xv[k4];
        #pragma unroll
        for (int i = 0; i < 4; ++i) {
            float xs = (i == 0) ? xk.x : (i == 1) ? xk.y : (i == 2) ? xk.z : xk.w;
            float4 w = W4[(k4 * 4 + i) * 16 + jq];
            acc.x += xs * w.x; acc.y += xs * w.y; acc.z += xs * w.z; acc.w += xs * w.w;
        }
    }
    ((float4*)h)[tid] = acc;
}

// ---------------- fused edge MLP + per-edge matvec + scatter ----------------
// 256 thr: o = t>>2 (output dim), (t&3) picks an 8-wide h-subrange.
// We chunk (2048 cols x 16 k, f16) staged in LDS with 16B-unit XOR swizzle.
__device__ __forceinline__ int swz(int u) { return u ^ ((u >> 9) & 6) ^ ((u >> 4) & 1); }

__global__ __launch_bounds__(256, 2) void k_edge(
    const f16x2* __restrict__ eaH,     // [E][8]
    const f16x2* __restrict__ weT,     // layer base: [4096][8]
    const float* __restrict__ be,      // layer base: [4096]
    const float* __restrict__ hin,     // [N][64]
    const int* __restrict__ srcI,
    const int* __restrict__ dstI,
    float* __restrict__ agg,
    int E, int perBlock)
{
    __shared__ __align__(16) _Float16 weL[2048 * 16];   // 64 KB
    __shared__ float beL[2048];                          // 8 KB
    const int t = threadIdx.x;
    const int o = t >> 2;
    const int hsub = (t & 3) * 8;
    int e_begin = blockIdx.x * perBlock;
    int e_end = min(e_begin + perBlock, E);

    for (int phase = 0; phase < 2; ++phase) {
        __syncthreads();   // protect previous phase's reads
        {
            const uint4* g = ((const uint4*)weT) + phase * 4096;
            uint4* s4 = (uint4*)weL;
            #pragma unroll
            for (int it = 0; it < 16; ++it) {
                int u = it * 256 + t;
                s4[swz(u)] = g[u];
            }
            const float4* bg = (const float4*)(be + phase * 2048);
            float4* bs = (float4*)beL;
            for (int i = t; i < 512; i += 256) bs[i] = bg[i];
        }
        __syncthreads();
        const int hbase = phase * 32 + hsub;

        for (int e0 = e_begin; e0 < e_end; e0 += 8) {
            float hs[8][8];
            f16x2 ea[8][8];
            #pragma unroll
            for (int e = 0; e < 8; ++e) {
                int ei = e0 + e;
                bool v = ei < e_end;
                int s = v ? srcI[ei] : 0;
                const float4* hp = (const float4*)(hin + (size_t)s * HDIM + hbase);
                float4 ha = hp[0], hb = hp[1];
                if (!v) { ha = make_float4(0, 0, 0, 0); hb = ha; }
                hs[e][0] = ha.x; hs[e][1] = ha.y; hs[e][2] = ha.z; hs[e][3] = ha.w;
                hs[e][4] = hb.x; hs[e][5] = hb.y; hs[e][6] = hb.z; hs[e][7] = hb.w;
                const f16x8* ep = (const f16x8*)(eaH + (size_t)(v ? ei : 0) * 8);
                f16x8 a0 = ep[0], a1 = ep[1];
                #pragma unroll
                for (int j = 0; j < 4; ++j) {
                    f16x2 p; p[0] = a0[2 * j]; p[1] = a0[2 * j + 1]; ea[e][j] = p;
                    f16x2 q; q[0] = a1[2 * j]; q[1] = a1[2 * j + 1]; ea[e][4 + j] = q;
                }
            }
            float msg[8];
            #pragma unroll
            for (int e = 0; e < 8; ++e) msg[e] = 0.f;

            #pragma unroll
            for (int hh = 0; hh < 8; ++hh) {
                int lcol = (hsub + hh) * 64 + o;          // phase-independent local col
                int su = swz(lcol * 2);
                const uint4* wl = (const uint4*)weL;
                uint4 wa_ = wl[su];
                uint4 wb_ = wl[su ^ 1];
                f16x8 wa = __builtin_bit_cast(f16x8, wa_);
                f16x8 wb = __builtin_bit_cast(f16x8, wb_);
                f16x2 wv[8];
                #pragma unroll
                for (int j = 0; j < 4; ++j) {
                    f16x2 p; p[0] = wa[2 * j]; p[1] = wa[2 * j + 1]; wv[j] = p;
                    f16x2 q; q[0] = wb[2 * j]; q[1] = wb[2 * j + 1]; wv[4 + j] = q;
                }
                float bec = beL[lcol];
                #pragma unroll
                for (int e = 0; e < 8; ++e) {
                    float z = bec;
                    #pragma unroll
                    for (int j = 0; j < 8; ++j) z = fdot2(ea[e][j], wv[j], z);
                    msg[e] += fmaxf(z, 0.f) * hs[e][hh];
                }
            }
            #pragma unroll
            for (int e = 0; e < 8; ++e) {
                float m = msg[e];
                m += __shfl_xor(m, 1);
                m += __shfl_xor(m, 2);
                if ((t & 3) == 0) {
                    int ei = e0 + e;
                    if (ei < e_end) atomicAdd(&agg[(size_t)dstI[ei] * HDIM + o], m);
                }
            }
        }
    }
}

// ---------------- node update: mean, root GEMV, relu, BN(eval), residual ----------------
__global__ void k_update(
    const float* __restrict__ agg, const float* __restrict__ deg,
    const float* __restrict__ hin, const float* __restrict__ Wroot,   // layer base [64][64]
    const float* __restrict__ broot, const float* __restrict__ gam,
    const float* __restrict__ bet, const float* __restrict__ rmean,
    const float* __restrict__ rvar, float* __restrict__ hout, int N)
{
    int tid = blockIdx.x * 256 + threadIdx.x;   // N*16
    int n = tid >> 4, jq = tid & 15;
    if (n >= N) return;
    float dinv = 1.0f / fmaxf(deg[n], 1.0f);
    float4 acc = ((const float4*)broot)[jq];
    float4 ag = ((const float4*)agg)[tid];
    acc.x += ag.x * dinv; acc.y += ag.y * dinv; acc.z += ag.z * dinv; acc.w += ag.w * dinv;
    const float4* W4 = (const float4*)Wroot;
    const float4* hv = (const float4*)(hin + (size_t)n * HDIM);
    #pragma unroll
    for (int k4 = 0; k4 < 16; ++k4) {
        float4 hk = hv[k4];
        #pragma unroll
        for (int i = 0; i < 4; ++i) {
            float hsc = (i == 0) ? hk.x : (i == 1) ? hk.y : (i == 2) ? hk.z : hk.w;
            float4 w = W4[(k4 * 4 + i) * 16 + jq];
            acc.x += hsc * w.x; acc.y += hsc * w.y; acc.z += hsc * w.z; acc.w += hsc * w.w;
        }
    }
    acc.x = fmaxf(acc.x, 0.f); acc.y = fmaxf(acc.y, 0.f);
    acc.z = fmaxf(acc.z, 0.f); acc.w = fmaxf(acc.w, 0.f);
    float4 g4 = ((const float4*)gam)[jq];
    float4 b4 = ((const float4*)bet)[jq];
    float4 m4 = ((const float4*)rmean)[jq];
    float4 v4 = ((const float4*)rvar)[jq];
    float4 hres = ((const float4*)hin)[tid];
    float4 y;
    y.x = g4.x * (acc.x - m4.x) * rsqrtf(v4.x + BN_EPS) + b4.x + hres.x;
    y.y = g4.y * (acc.y - m4.y) * rsqrtf(v4.y + BN_EPS) + b4.y + hres.y;
    y.z = g4.z * (acc.z - m4.z) * rsqrtf(v4.z + BN_EPS) + b4.z + hres.z;
    y.w = g4.w * (acc.w - m4.w) * rsqrtf(v4.w + BN_EPS) + b4.w + hres.w;
    ((float4*)hout)[tid] = y;
}

// ---------------- pooling + head ----------------
__global__ void k_pool(const float* __restrict__ h, const int* __restrict__ batch,
                       float* __restrict__ pooled, int N) {
    int tid = blockIdx.x * 256 + threadIdx.x;
    int n = tid >> 4, jq = tid & 15;
    if (n >= N) return;
    int g = batch[n];
    float4 v = ((const float4*)h)[tid];
    float* p = pooled + (size_t)g * HDIM + jq * 4;
    atomicAdd(p + 0, v.x); atomicAdd(p + 1, v.y);
    atomicAdd(p + 2, v.z); atomicAdd(p + 3, v.w);
}

__global__ __launch_bounds__(64) void k_head(
    const float* __restrict__ pooled, const float* __restrict__ bcnt,
    const float* __restrict__ W1, const float* __restrict__ b1,
    const float* __restrict__ W2, const float* __restrict__ b2,
    float* __restrict__ out) {
    __shared__ float pl[HDIM];
    __shared__ float zl[HDIM];
    int g = blockIdx.x, j = threadIdx.x;
    float binv = 1.0f / fmaxf(bcnt[g], 1.0f);
    pl[j] = pooled[(size_t)g * HDIM + j] * binv;
    __syncthreads();
    float acc = b1[j];
    #pragma unroll
    for (int k = 0; k < HDIM; ++k) acc += pl[k] * W1[k * HDIM + j];
    zl[j] = fmaxf(acc, 0.f);
    __syncthreads();
    if (j < OUT_DIM) {
        float a = b2[j];
        #pragma unroll
        for (int k = 0; k < HDIM; ++k) a += zl[k] * W2[k * OUT_DIM + j];
        out[(size_t)g * OUT_DIM + j] = a;
    }
}

// ---------------- launch ----------------
extern "C" void kernel_launch(void* const* d_in, const int* in_sizes, int n_in,
                              void* d_out, int out_size, void* d_ws, size_t ws_size,
                              hipStream_t stream) {
    const float* x     = (const float*)d_in[0];
    const float* eattr = (const float*)d_in[1];
    const int*   src   = (const int*)d_in[2];
    const int*   dst   = (const int*)d_in[3];
    const int*   batch = (const int*)d_in[4];
    const float* Wx    = (const float*)d_in[5];
    const float* bx    = (const float*)d_in[6];
    const float* We    = (const float*)d_in[7];
    const float* be    = (const float*)d_in[8];
    const float* Wroot = (const float*)d_in[9];
    const float* broot = (const float*)d_in[10];
    const float* gam   = (const float*)d_in[11];
    const float* bet   = (const float*)d_in[12];
    const float* rmean = (const float*)d_in[13];
    const float* rvar  = (const float*)d_in[14];
    const float* W1    = (const float*)d_in[15];
    const float* b1    = (const float*)d_in[16];
    const float* W2    = (const float*)d_in[17];
    const float* b2    = (const float*)d_in[18];
    float* out = (float*)d_out;

    const int N = in_sizes[0] / IN_DIM;
    const int E = in_sizes[2];
    const int G = out_size / OUT_DIM;

    char* ws = (char*)d_ws;
    size_t off = 0;
    auto alloc = [&](size_t bytes) -> void* {
        void* p = ws + off;
        off = (off + bytes + 255) & ~(size_t)255;
        return p;
    };
    float*    h0     = (float*)alloc((size_t)N * HDIM * 4);
    float*    h1     = (float*)alloc((size_t)N * HDIM * 4);
    float*    agg    = (float*)alloc((size_t)N * HDIM * 4);
    float*    deg    = (float*)alloc((size_t)N * 4);
    float*    bcnt   = (float*)alloc((size_t)G * 4);
    float*    pooled = (float*)alloc((size_t)G * HDIM * 4);
    f16x2*    eaH    = (f16x2*)alloc((size_t)E * 8 * 4);
    _Float16* WeT    = (_Float16*)alloc((size_t)3 * 65536 * 2);
    (void)ws_size; (void)n_in;

    hipMemsetAsync(deg, 0, (size_t)N * 4, stream);
    hipMemsetAsync(bcnt, 0, (size_t)G * 4, stream);
    hipMemsetAsync(pooled, 0, (size_t)G * HDIM * 4, stream);

    k_convert_we<<<(3 * 65536 + 255) / 256, 256, 0, stream>>>(We, WeT, 3 * 65536);
    k_convert_ea<<<(E * 8 + 255) / 256, 256, 0, stream>>>(eattr, eaH, E * 8);
    k_count<<<(E + 255) / 256, 256, 0, stream>>>(dst, deg, E);
    k_count<<<(N + 255) / 256, 256, 0, stream>>>(batch, bcnt, N);
    k_encode<<<(N * 16 + 255) / 256, 256, 0, stream>>>(x, Wx, bx, h0, N);

    const float* hin = h0;
    float* hout = h1;
    const int perBlock = (E + 511) / 512;
    for (int l = 0; l < 3; ++l) {
        hipMemsetAsync(agg, 0, (size_t)N * HDIM * 4, stream);
        k_edge<<<512, 256, 0, stream>>>(eaH, (const f16x2*)(WeT + (size_t)l * 65536),
                                        be + (size_t)l * 4096, hin, src, dst, agg, E, perBlock);
        k_update<<<(N * 16 + 255) / 256, 256, 0, stream>>>(
            agg, deg, hin, Wroot + (size_t)l * 4096, broot + (size_t)l * 64,
            gam + (size_t)l * 64, bet + (size_t)l * 64, rmean + (size_t)l * 64,
            rvar + (size_t)l * 64, hout, N);
        float* tmp = hout; hout = (float*)hin; hin = tmp;
    }
    k_pool<<<(N * 16 + 255) / 256, 256, 0, stream>>>(hin, batch, pooled, N);
    k_head<<<G, 64, 0, stream>>>(pooled, bcnt, W1, b1, W2, b2, out);
}

// Round 2
// 340.409 us; speedup vs baseline: 1.8406x; 1.8406x over previous
//
#include <hip/hip_runtime.h>
#include <hip/hip_bf16.h>

typedef _Float16 f16x2 __attribute__((ext_vector_type(2)));
typedef _Float16 f16x8 __attribute__((ext_vector_type(8)));
typedef float    f32x4 __attribute__((ext_vector_type(4)));

#define IN_DIM   32
#define EDGE_DIM 16
#define HDIM     64
#define OUT_DIM  6
#define BN_EPS   1e-5f

// ---------------- prep: convert edge_attr to f16 + degree/batch counts ----------------
__global__ void k_prep(const float* __restrict__ ea, _Float16* __restrict__ eaH,
                       const int* __restrict__ dstI, float* __restrict__ deg,
                       const int* __restrict__ batch, float* __restrict__ bcnt,
                       int E, int N) {
    int tid = blockIdx.x * 256 + threadIdx.x;
    int E8 = E * 8;
    if (tid < E8) {
        float2 v = ((const float2*)ea)[tid];
        f16x2 r; r[0] = (_Float16)v.x; r[1] = (_Float16)v.y;
        ((f16x2*)eaH)[tid] = r;
    }
    if (tid < E) atomicAdd(&deg[dstI[tid]], 1.0f);
    if (tid < N) atomicAdd(&bcnt[batch[tid]], 1.0f);
}

// ---------------- pack We into MFMA B-fragment order ----------------
// out: [3 layers][256 tiles][32 lanes] x 16B. lane: col=lane&15, kslot=lane>>4 (0/1),
// elem j -> We[layer][kslot*8+j][tile*16 + (lane&15)]
__global__ void k_pack_we(const float* __restrict__ We, uint4* __restrict__ WeB, int total) {
    int tid = blockIdx.x * 256 + threadIdx.x;
    if (tid >= total) return;                 // total = 3*256*32
    int layer = tid >> 13;
    int r = tid & 8191;
    int tile = r >> 5, lane = r & 31;
    int kslot = lane >> 4, col = tile * 16 + (lane & 15);
    const float* base = We + (size_t)layer * 65536 + col;
    f16x8 v;
    #pragma unroll
    for (int j = 0; j < 8; ++j) v[j] = (_Float16)base[(kslot * 8 + j) * 4096];
    WeB[tid] = __builtin_bit_cast(uint4, v);
}

// ---------------- node encoder: h = x @ Wx + bx ----------------
__global__ void k_encode(const float* __restrict__ x, const float* __restrict__ Wx,
                         const float* __restrict__ bx, float* __restrict__ h, int N) {
    int tid = blockIdx.x * 256 + threadIdx.x;      // N*16 threads, float4 over j
    int n = tid >> 4, jq = tid & 15;
    if (n >= N) return;
    const float4* W4 = (const float4*)Wx;
    float4 acc = ((const float4*)bx)[jq];
    const float4* xv = (const float4*)(x + (size_t)n * IN_DIM);
    #pragma unroll
    for (int k4 = 0; k4 < 8; ++k4) {
        float4 xk = xv[k4];
        #pragma unroll
        for (int i = 0; i < 4; ++i) {
            float xs = (i == 0) ? xk.x : (i == 1) ? xk.y : (i == 2) ? xk.z : xk.w;
            float4 w = W4[(k4 * 4 + i) * 16 + jq];
            acc.x += xs * w.x; acc.y += xs * w.y; acc.z += xs * w.z; acc.w += xs * w.w;
        }
    }
    ((float4*)h)[tid] = acc;
}

// ---------------- fused edge MLP (MFMA) + per-edge weighted reduce + scatter ----------------
// Block: 64 edges, 4 waves. Wave w: edge-pair-group gp=w>>1 (32 edges), h-half = w&1 (32 h).
// Per wave: 2 MFMA groups of 16 edges; B fragments streamed from L2 (prepacked);
// hs = hin[src] staged transposed in LDS once per block.
__global__ __launch_bounds__(256, 2) void k_edge(
    const uint4* __restrict__ eaH,      // [E][2] uint4  (= [E][16] f16)
    const uint4* __restrict__ WeB,      // layer base: [256][32] uint4 fragments
    const float* __restrict__ be,       // layer base: [4096]
    const float* __restrict__ hin,      // [N][64]
    const int* __restrict__ srcI,
    const int* __restrict__ dstI,
    float* __restrict__ agg,
    int E)
{
    __shared__ float hsT[64][68];       // [h][edge_local], pad 68 (bank-spread)
    const int t = threadIdx.x;
    const int l = t & 63;
    const int w = t >> 6;
    const int eb = blockIdx.x * 64;

    // ---- stage hsT: 64 edges x 64 h, transposed ----
    {
        int el = t >> 2;                 // 0..63 local edge
        int hq = t & 3;                  // 16-h quad
        int eg = min(eb + el, E - 1);
        int s = srcI[eg];
        const float4* hp = (const float4*)(hin + (size_t)s * HDIM + hq * 16);
        float4 a = hp[0], b = hp[1], c = hp[2], d = hp[3];
        float v[16] = {a.x,a.y,a.z,a.w, b.x,b.y,b.z,b.w, c.x,c.y,c.z,c.w, d.x,d.y,d.z,d.w};
        #pragma unroll
        for (int i = 0; i < 16; ++i) hsT[hq * 16 + i][el] = v[i];
    }
    __syncthreads();

    const int gp  = w >> 1;              // 0/1 : which 32-edge half of the block
    const int h0  = (w & 1) * 32;        // h range
    const int ebw = eb + gp * 32;        // global edge base for this wave
    const int elw = gp * 32;             // local edge base in hsT
    const int g   = l >> 4;              // k-slot group 0..3
    const int g4  = g * 4;
    const int c16 = l & 15;

    // ---- A fragments (16 edges each, K=16 real, upper K zeros) ----
    f16x8 A0 = {}, A1 = {};
    if (g < 2) {
        int e0 = min(ebw + c16, E - 1);
        int e1 = min(ebw + 16 + c16, E - 1);
        A0 = __builtin_bit_cast(f16x8, eaH[e0 * 2 + g]);
        A1 = __builtin_bit_cast(f16x8, eaH[e1 * 2 + g]);
    }
    // ---- bias per o_tile (rides as MFMA C-in; uniform over rows) ----
    float bias[4];
    #pragma unroll
    for (int o = 0; o < 4; ++o) bias[o] = be[o * 16 + c16];

    f32x4 acc0[4], acc1[4];
    #pragma unroll
    for (int o = 0; o < 4; ++o) { acc0[o] = (f32x4)0.f; acc1[o] = (f32x4)0.f; }

    const uint4* Bbase = WeB + (size_t)(l & 31);
    // prefetch h0's 4 fragments
    uint4 Bv0 = Bbase[(size_t)(h0 * 4 + 0) * 32];
    uint4 Bv1 = Bbase[(size_t)(h0 * 4 + 1) * 32];
    uint4 Bv2 = Bbase[(size_t)(h0 * 4 + 2) * 32];
    uint4 Bv3 = Bbase[(size_t)(h0 * 4 + 3) * 32];

    for (int hh = 0; hh < 32; ++hh) {
        const int h = h0 + hh;
        uint4 Bn0, Bn1, Bn2, Bn3;
        if (hh < 31) {
            const uint4* Bp = Bbase + (size_t)((h + 1) * 4) * 32;
            Bn0 = Bp[0]; Bn1 = Bp[32]; Bn2 = Bp[64]; Bn3 = Bp[96];
        }
        // hs values for this h: 2 groups x 4 rows (b64 broadcast reads)
        float2 p00 = *(const float2*)&hsT[h][elw + g4 + 0];
        float2 p01 = *(const float2*)&hsT[h][elw + g4 + 2];
        float2 p10 = *(const float2*)&hsT[h][elw + 16 + g4 + 0];
        float2 p11 = *(const float2*)&hsT[h][elw + 16 + g4 + 2];

        uint4 Bcur[4] = {Bv0, Bv1, Bv2, Bv3};
        #pragma unroll
        for (int o = 0; o < 4; ++o) {
            f16x8 B = __builtin_bit_cast(f16x8, Bcur[o]);
            f32x4 cin = {bias[o], bias[o], bias[o], bias[o]};
            f32x4 z0 = __builtin_amdgcn_mfma_f32_16x16x32_f16(A0, B, cin, 0, 0, 0);
            f32x4 z1 = __builtin_amdgcn_mfma_f32_16x16x32_f16(A1, B, cin, 0, 0, 0);
            acc0[o][0] += fmaxf(z0[0], 0.f) * p00.x;
            acc0[o][1] += fmaxf(z0[1], 0.f) * p00.y;
            acc0[o][2] += fmaxf(z0[2], 0.f) * p01.x;
            acc0[o][3] += fmaxf(z0[3], 0.f) * p01.y;
            acc1[o][0] += fmaxf(z1[0], 0.f) * p10.x;
            acc1[o][1] += fmaxf(z1[1], 0.f) * p10.y;
            acc1[o][2] += fmaxf(z1[2], 0.f) * p11.x;
            acc1[o][3] += fmaxf(z1[3], 0.f) * p11.y;
        }
        Bv0 = Bn0; Bv1 = Bn1; Bv2 = Bn2; Bv3 = Bn3;
    }

    // ---- scatter: partial sums (one per h-half) to agg via atomics ----
    #pragma unroll
    for (int grp = 0; grp < 2; ++grp) {
        #pragma unroll
        for (int r = 0; r < 4; ++r) {
            int e = ebw + grp * 16 + g4 + r;
            if (e < E) {
                int d = dstI[e];
                float* base = agg + (size_t)d * HDIM + c16;
                #pragma unroll
                for (int o = 0; o < 4; ++o) {
                    float val = grp == 0 ? acc0[o][r] : acc1[o][r];
                    atomicAdd(base + o * 16, val);
                }
            }
        }
    }
}

// ---------------- node update: mean, root GEMV, relu, BN(eval), residual; zeroes agg ----------------
__global__ void k_update(
    float* __restrict__ agg, const float* __restrict__ deg,
    const float* __restrict__ hin, const float* __restrict__ Wroot,   // layer base [64][64]
    const float* __restrict__ broot, const float* __restrict__ gam,
    const float* __restrict__ bet, const float* __restrict__ rmean,
    const float* __restrict__ rvar, float* __restrict__ hout, int N)
{
    int tid = blockIdx.x * 256 + threadIdx.x;   // N*16
    int n = tid >> 4, jq = tid & 15;
    if (n >= N) return;
    float dinv = 1.0f / fmaxf(deg[n], 1.0f);
    float4 acc = ((const float4*)broot)[jq];
    float4 ag = ((const float4*)agg)[tid];
    ((float4*)agg)[tid] = make_float4(0.f, 0.f, 0.f, 0.f);   // self-clean for next layer
    acc.x += ag.x * dinv; acc.y += ag.y * dinv; acc.z += ag.z * dinv; acc.w += ag.w * dinv;
    const float4* W4 = (const float4*)Wroot;
    const float4* hv = (const float4*)(hin + (size_t)n * HDIM);
    #pragma unroll
    for (int k4 = 0; k4 < 16; ++k4) {
        float4 hk = hv[k4];
        #pragma unroll
        for (int i = 0; i < 4; ++i) {
            float hsc = (i == 0) ? hk.x : (i == 1) ? hk.y : (i == 2) ? hk.z : hk.w;
            float4 w = W4[(k4 * 4 + i) * 16 + jq];
            acc.x += hsc * w.x; acc.y += hsc * w.y; acc.z += hsc * w.z; acc.w += hsc * w.w;
        }
    }
    acc.x = fmaxf(acc.x, 0.f); acc.y = fmaxf(acc.y, 0.f);
    acc.z = fmaxf(acc.z, 0.f); acc.w = fmaxf(acc.w, 0.f);
    float4 g4 = ((const float4*)gam)[jq];
    float4 b4 = ((const float4*)bet)[jq];
    float4 m4 = ((const float4*)rmean)[jq];
    float4 v4 = ((const float4*)rvar)[jq];
    float4 hres = ((const float4*)hin)[tid];
    float4 y;
    y.x = g4.x * (acc.x - m4.x) * rsqrtf(v4.x + BN_EPS) + b4.x + hres.x;
    y.y = g4.y * (acc.y - m4.y) * rsqrtf(v4.y + BN_EPS) + b4.y + hres.y;
    y.z = g4.z * (acc.z - m4.z) * rsqrtf(v4.z + BN_EPS) + b4.z + hres.z;
    y.w = g4.w * (acc.w - m4.w) * rsqrtf(v4.w + BN_EPS) + b4.w + hres.w;
    ((float4*)hout)[tid] = y;
}

// ---------------- pooling (sorted batch -> chunked partial sums) + head ----------------
__global__ void k_pool(const float* __restrict__ h, const int* __restrict__ batch,
                       float* __restrict__ pooled, int N) {
    int tid = blockIdx.x * 256 + threadIdx.x;
    int chunk = tid >> 4, jq = tid & 15;
    int n0 = chunk * 16;
    if (n0 >= N) return;
    int nend = min(n0 + 16, N);
    float4 acc = make_float4(0.f, 0.f, 0.f, 0.f);
    int gcur = batch[n0];
    for (int n = n0; n < nend; ++n) {
        int gn = batch[n];
        if (gn != gcur) {
            float* p = pooled + (size_t)gcur * HDIM + jq * 4;
            atomicAdd(p + 0, acc.x); atomicAdd(p + 1, acc.y);
            atomicAdd(p + 2, acc.z); atomicAdd(p + 3, acc.w);
            acc = make_float4(0.f, 0.f, 0.f, 0.f);
            gcur = gn;
        }
        float4 v = ((const float4*)h)[(size_t)n * 16 + jq];
        acc.x += v.x; acc.y += v.y; acc.z += v.z; acc.w += v.w;
    }
    float* p = pooled + (size_t)gcur * HDIM + jq * 4;
    atomicAdd(p + 0, acc.x); atomicAdd(p + 1, acc.y);
    atomicAdd(p + 2, acc.z); atomicAdd(p + 3, acc.w);
}

__global__ __launch_bounds__(64) void k_head(
    const float* __restrict__ pooled, const float* __restrict__ bcnt,
    const float* __restrict__ W1, const float* __restrict__ b1,
    const float* __restrict__ W2, const float* __restrict__ b2,
    float* __restrict__ out) {
    __shared__ float pl[HDIM];
    __shared__ float zl[HDIM];
    int g = blockIdx.x, j = threadIdx.x;
    float binv = 1.0f / fmaxf(bcnt[g], 1.0f);
    pl[j] = pooled[(size_t)g * HDIM + j] * binv;
    __syncthreads();
    float acc = b1[j];
    #pragma unroll
    for (int k = 0; k < HDIM; ++k) acc += pl[k] * W1[k * HDIM + j];
    zl[j] = fmaxf(acc, 0.f);
    __syncthreads();
    if (j < OUT_DIM) {
        float a = b2[j];
        #pragma unroll
        for (int k = 0; k < HDIM; ++k) a += zl[k] * W2[k * OUT_DIM + j];
        out[(size_t)g * OUT_DIM + j] = a;
    }
}

// ---------------- launch ----------------
extern "C" void kernel_launch(void* const* d_in, const int* in_sizes, int n_in,
                              void* d_out, int out_size, void* d_ws, size_t ws_size,
                              hipStream_t stream) {
    const float* x     = (const float*)d_in[0];
    const float* eattr = (const float*)d_in[1];
    const int*   src   = (const int*)d_in[2];
    const int*   dst   = (const int*)d_in[3];
    const int*   batch = (const int*)d_in[4];
    const float* Wx    = (const float*)d_in[5];
    const float* bx    = (const float*)d_in[6];
    const float* We    = (const float*)d_in[7];
    const float* be    = (const float*)d_in[8];
    const float* Wroot = (const float*)d_in[9];
    const float* broot = (const float*)d_in[10];
    const float* gam   = (const float*)d_in[11];
    const float* bet   = (const float*)d_in[12];
    const float* rmean = (const float*)d_in[13];
    const float* rvar  = (const float*)d_in[14];
    const float* W1    = (const float*)d_in[15];
    const float* b1    = (const float*)d_in[16];
    const float* W2    = (const float*)d_in[17];
    const float* b2    = (const float*)d_in[18];
    float* out = (float*)d_out;

    const int N = in_sizes[0] / IN_DIM;
    const int E = in_sizes[2];
    const int G = out_size / OUT_DIM;

    char* ws = (char*)d_ws;
    size_t off = 0;
    auto alloc = [&](size_t bytes) -> void* {
        void* p = ws + off;
        off = (off + bytes + 255) & ~(size_t)255;
        return p;
    };
    float*    h0    = (float*)alloc((size_t)N * HDIM * 4);
    float*    h1    = (float*)alloc((size_t)N * HDIM * 4);
    _Float16* eaH   = (_Float16*)alloc((size_t)E * 16 * 2);
    uint4*    WeB   = (uint4*)alloc((size_t)3 * 256 * 32 * 16);
    // contiguous zero region: deg, bcnt, pooled, agg
    char*  zbase   = ws + off;
    float* deg     = (float*)alloc((size_t)N * 4);
    float* bcnt    = (float*)alloc((size_t)G * 4);
    float* pooled  = (float*)alloc((size_t)G * HDIM * 4);
    float* agg     = (float*)alloc((size_t)N * HDIM * 4);
    size_t zbytes  = (size_t)((ws + off) - zbase);
    (void)ws_size; (void)n_in;

    hipMemsetAsync(zbase, 0, zbytes, stream);

    int prepThreads = E * 8;   // covers E and N too
    k_prep<<<(prepThreads + 255) / 256, 256, 0, stream>>>(eattr, eaH, dst, deg, batch, bcnt, E, N);
    k_pack_we<<<(3 * 256 * 32 + 255) / 256, 256, 0, stream>>>(We, WeB, 3 * 256 * 32);
    k_encode<<<(N * 16 + 255) / 256, 256, 0, stream>>>(x, Wx, bx, h0, N);

    const float* hin = h0;
    float* hout = h1;
    const int edgeBlocks = (E + 63) / 64;
    for (int l = 0; l < 3; ++l) {
        k_edge<<<edgeBlocks, 256, 0, stream>>>(
            (const uint4*)eaH, WeB + (size_t)l * 8192, be + (size_t)l * 4096,
            hin, src, dst, agg, E);
        k_update<<<(N * 16 + 255) / 256, 256, 0, stream>>>(
            agg, deg, hin, Wroot + (size_t)l * 4096, broot + (size_t)l * 64,
            gam + (size_t)l * 64, bet + (size_t)l * 64, rmean + (size_t)l * 64,
            rvar + (size_t)l * 64, hout, N);
        float* tmp = hout; hout = (float*)hin; hin = tmp;
    }
    k_pool<<<((N + 15) / 16 * 16 + 255) / 256, 256, 0, stream>>>(hin, batch, pooled, N);
    k_head<<<G, 64, 0, stream>>>(pooled, bcnt, W1, b1, W2, b2, out);
}

// Round 3
// 228.178 us; speedup vs baseline: 2.7459x; 1.4919x over previous
//
#include <hip/hip_runtime.h>
#include <hip/hip_bf16.h>

typedef _Float16 f16x2 __attribute__((ext_vector_type(2)));
typedef _Float16 f16x8 __attribute__((ext_vector_type(8)));
typedef float    f32x4 __attribute__((ext_vector_type(4)));

#define IN_DIM   32
#define EDGE_DIM 16
#define HDIM     64
#define OUT_DIM  6
#define BN_EPS   1e-5f

// ---------------- prep: convert edge_attr to f16 + degree counts ----------------
__global__ void k_prep(const float* __restrict__ ea, _Float16* __restrict__ eaH,
                       const int* __restrict__ dstI, float* __restrict__ deg, int E) {
    int tid = blockIdx.x * 256 + threadIdx.x;
    int E8 = E * 8;
    if (tid < E8) {
        float2 v = ((const float2*)ea)[tid];
        f16x2 r; r[0] = (_Float16)v.x; r[1] = (_Float16)v.y;
        ((f16x2*)eaH)[tid] = r;
    }
    if (tid < E) atomicAdd(&deg[dstI[tid]], 1.0f);
}

// ---------------- graph segment bounds (batch is sorted): start[g], g=0..G ----------------
__global__ void k_bounds(const int* __restrict__ batch, int* __restrict__ start, int N, int G) {
    int g = threadIdx.x;
    if (g > G) return;
    int lo = 0, hi = N;
    while (lo < hi) { int mid = (lo + hi) >> 1; if (batch[mid] < g) lo = mid + 1; else hi = mid; }
    start[g] = lo;
}

// ---------------- pack We into MFMA B-fragment order (LDS-staged, coalesced) ----------------
// WeB[layer][tile=h*4+o][lane<32] 16B: lane col=lane&15, kslot=lane>>4,
// elem j = We[layer][kslot*8+j][tile*16 + (lane&15)]
__global__ void k_pack_we(const float* __restrict__ We, uint4* __restrict__ WeB) {
    __shared__ float w[2048];                  // 16 k x 128 cols
    int b = blockIdx.x;                        // 3 layers * 32 chunks
    int layer = b >> 5, chunk = b & 31;
    int colbase = chunk * 128;
    int t = threadIdx.x;
    #pragma unroll
    for (int i = 0; i < 8; ++i) {
        int idx = i * 256 + t;
        int k = idx >> 7, c = idx & 127;
        w[idx] = We[(size_t)layer * 65536 + k * 4096 + colbase + c];
    }
    __syncthreads();
    int tile = t >> 5, lane = t & 31;          // 8 tiles per block
    int kslot = lane >> 4, col = tile * 16 + (lane & 15);
    f16x8 v;
    #pragma unroll
    for (int j = 0; j < 8; ++j) v[j] = (_Float16)w[(kslot * 8 + j) * 128 + col];
    WeB[(size_t)layer * 8192 + (size_t)(chunk * 8 + tile) * 32 + lane] = __builtin_bit_cast(uint4, v);
}

// ---------------- node encoder: h = x @ Wx + bx ----------------
__global__ void k_encode(const float* __restrict__ x, const float* __restrict__ Wx,
                         const float* __restrict__ bx, float* __restrict__ h, int N) {
    int tid = blockIdx.x * 256 + threadIdx.x;      // N*16 threads, float4 over j
    int n = tid >> 4, jq = tid & 15;
    if (n >= N) return;
    const float4* W4 = (const float4*)Wx;
    float4 acc = ((const float4*)bx)[jq];
    const float4* xv = (const float4*)(x + (size_t)n * IN_DIM);
    #pragma unroll
    for (int k4 = 0; k4 < 8; ++k4) {
        float4 xk = xv[k4];
        #pragma unroll
        for (int i = 0; i < 4; ++i) {
            float xs = (i == 0) ? xk.x : (i == 1) ? xk.y : (i == 2) ? xk.z : xk.w;
            float4 w = W4[(k4 * 4 + i) * 16 + jq];
            acc.x += xs * w.x; acc.y += xs * w.y; acc.z += xs * w.z; acc.w += xs * w.w;
        }
    }
    ((float4*)h)[tid] = acc;
}

// ---------------- fused edge MLP (MFMA) + weighted reduce + scatter ----------------
// Block: 64 edges, 4 waves. Wave w: edge-half gp=w>>1 (32 edges), o-half oh=w&1 (32 outs).
// Each (e,o) owned by exactly ONE wave -> E*64 atomics total per layer.
__global__ __launch_bounds__(256, 4) void k_edge(
    const uint4* __restrict__ eaH,      // [E][2] uint4  (= [E][16] f16)
    const uint4* __restrict__ WeB,      // layer base: [256 tiles][32] uint4
    const float* __restrict__ be,       // layer base: [4096] = [h*64+o]
    const float* __restrict__ hin,      // [N][64]
    const int* __restrict__ srcI,
    const int* __restrict__ dstI,
    float* __restrict__ agg,
    int E)
{
    __shared__ float hsT[64][68];       // [h][edge_local]
    const int t = threadIdx.x;
    const int l = t & 63;
    const int w = t >> 6;
    const int eb = blockIdx.x * 64;

    // ---- stage hsT: 64 edges x 64 h, transposed ----
    {
        int el = t >> 2;                 // local edge
        int hq = t & 3;                  // 16-h quad
        int eg = min(eb + el, E - 1);
        int s = srcI[eg];
        const float4* hp = (const float4*)(hin + (size_t)s * HDIM + hq * 16);
        float4 a = hp[0], b = hp[1], c = hp[2], d = hp[3];
        float v[16] = {a.x,a.y,a.z,a.w, b.x,b.y,b.z,b.w, c.x,c.y,c.z,c.w, d.x,d.y,d.z,d.w};
        #pragma unroll
        for (int i = 0; i < 16; ++i) hsT[hq * 16 + i][el] = v[i];
    }
    __syncthreads();

    const int gp  = w >> 1;
    const int oh  = w & 1;               // o-tiles {oh*2, oh*2+1} -> cols oh*32 + {0,16} + c16
    const int ebw = eb + gp * 32;
    const int elw = gp * 32;
    const int g   = l >> 4;
    const int g4  = g * 4;
    const int c16 = l & 15;

    // ---- A fragments: 16 edges each, K=16 real (upper 16 k are zero) ----
    f16x8 A0 = {}, A1 = {};
    if (g < 2) {
        int e0 = min(ebw + c16, E - 1);
        int e1 = min(ebw + 16 + c16, E - 1);
        A0 = __builtin_bit_cast(f16x8, eaH[(size_t)e0 * 2 + g]);
        A1 = __builtin_bit_cast(f16x8, eaH[(size_t)e1 * 2 + g]);
    }

    f32x4 acc0[2], acc1[2];
    acc0[0] = (f32x4)0.f; acc0[1] = (f32x4)0.f;
    acc1[0] = (f32x4)0.f; acc1[1] = (f32x4)0.f;

    const uint4* Bbase = WeB + (size_t)(l & 31);
    uint4 Bv0 = Bbase[(size_t)(oh * 2 + 0) * 32];
    uint4 Bv1 = Bbase[(size_t)(oh * 2 + 1) * 32];

    for (int h = 0; h < 64; ++h) {
        uint4 Bn0, Bn1;
        if (h < 63) {
            const uint4* Bp = Bbase + (size_t)((h + 1) * 4 + oh * 2) * 32;
            Bn0 = Bp[0]; Bn1 = Bp[32];
        }
        float4 p0 = *(const float4*)&hsT[h][elw + g4];
        float4 p1 = *(const float4*)&hsT[h][elw + 16 + g4];
        float bia0 = be[h * 64 + oh * 32 + c16];
        float bia1 = be[h * 64 + oh * 32 + 16 + c16];

        {
            f16x8 B = __builtin_bit_cast(f16x8, Bv0);
            f32x4 cin = {bia0, bia0, bia0, bia0};
            f32x4 z0 = __builtin_amdgcn_mfma_f32_16x16x32_f16(A0, B, cin, 0, 0, 0);
            f32x4 z1 = __builtin_amdgcn_mfma_f32_16x16x32_f16(A1, B, cin, 0, 0, 0);
            acc0[0][0] += fmaxf(z0[0], 0.f) * p0.x;
            acc0[0][1] += fmaxf(z0[1], 0.f) * p0.y;
            acc0[0][2] += fmaxf(z0[2], 0.f) * p0.z;
            acc0[0][3] += fmaxf(z0[3], 0.f) * p0.w;
            acc1[0][0] += fmaxf(z1[0], 0.f) * p1.x;
            acc1[0][1] += fmaxf(z1[1], 0.f) * p1.y;
            acc1[0][2] += fmaxf(z1[2], 0.f) * p1.z;
            acc1[0][3] += fmaxf(z1[3], 0.f) * p1.w;
        }
        {
            f16x8 B = __builtin_bit_cast(f16x8, Bv1);
            f32x4 cin = {bia1, bia1, bia1, bia1};
            f32x4 z0 = __builtin_amdgcn_mfma_f32_16x16x32_f16(A0, B, cin, 0, 0, 0);
            f32x4 z1 = __builtin_amdgcn_mfma_f32_16x16x32_f16(A1, B, cin, 0, 0, 0);
            acc0[1][0] += fmaxf(z0[0], 0.f) * p0.x;
            acc0[1][1] += fmaxf(z0[1], 0.f) * p0.y;
            acc0[1][2] += fmaxf(z0[2], 0.f) * p0.z;
            acc0[1][3] += fmaxf(z0[3], 0.f) * p0.w;
            acc1[1][0] += fmaxf(z1[0], 0.f) * p1.x;
            acc1[1][1] += fmaxf(z1[1], 0.f) * p1.y;
            acc1[1][2] += fmaxf(z1[2], 0.f) * p1.z;
            acc1[1][3] += fmaxf(z1[3], 0.f) * p1.w;
        }
        Bv0 = Bn0; Bv1 = Bn1;
    }

    // ---- scatter: one atomic per (e,o) owned by this wave ----
    #pragma unroll
    for (int grp = 0; grp < 2; ++grp) {
        #pragma unroll
        for (int r = 0; r < 4; ++r) {
            int e = ebw + grp * 16 + g4 + r;
            if (e < E) {
                int d = dstI[e];
                float* base = agg + (size_t)d * HDIM + oh * 32 + c16;
                float v0 = grp == 0 ? acc0[0][r] : acc1[0][r];
                float v1 = grp == 0 ? acc0[1][r] : acc1[1][r];
                atomicAdd(base + 0,  v0);
                atomicAdd(base + 16, v1);
            }
        }
    }
}

// ---------------- node update: mean, root GEMV, relu, BN(eval), residual; zeroes agg ----------------
__global__ void k_update(
    float* __restrict__ agg, const float* __restrict__ deg,
    const float* __restrict__ hin, const float* __restrict__ Wroot,
    const float* __restrict__ broot, const float* __restrict__ gam,
    const float* __restrict__ bet, const float* __restrict__ rmean,
    const float* __restrict__ rvar, float* __restrict__ hout, int N)
{
    int tid = blockIdx.x * 256 + threadIdx.x;   // N*16
    int n = tid >> 4, jq = tid & 15;
    if (n >= N) return;
    float dinv = 1.0f / fmaxf(deg[n], 1.0f);
    float4 acc = ((const float4*)broot)[jq];
    float4 ag = ((const float4*)agg)[tid];
    ((float4*)agg)[tid] = make_float4(0.f, 0.f, 0.f, 0.f);   // self-clean for next layer
    acc.x += ag.x * dinv; acc.y += ag.y * dinv; acc.z += ag.z * dinv; acc.w += ag.w * dinv;
    const float4* W4 = (const float4*)Wroot;
    const float4* hv = (const float4*)(hin + (size_t)n * HDIM);
    #pragma unroll
    for (int k4 = 0; k4 < 16; ++k4) {
        float4 hk = hv[k4];
        #pragma unroll
        for (int i = 0; i < 4; ++i) {
            float hsc = (i == 0) ? hk.x : (i == 1) ? hk.y : (i == 2) ? hk.z : hk.w;
            float4 w = W4[(k4 * 4 + i) * 16 + jq];
            acc.x += hsc * w.x; acc.y += hsc * w.y; acc.z += hsc * w.z; acc.w += hsc * w.w;
        }
    }
    acc.x = fmaxf(acc.x, 0.f); acc.y = fmaxf(acc.y, 0.f);
    acc.z = fmaxf(acc.z, 0.f); acc.w = fmaxf(acc.w, 0.f);
    float4 g4 = ((const float4*)gam)[jq];
    float4 b4 = ((const float4*)bet)[jq];
    float4 m4 = ((const float4*)rmean)[jq];
    float4 v4 = ((const float4*)rvar)[jq];
    float4 hres = ((const float4*)hin)[tid];
    float4 y;
    y.x = g4.x * (acc.x - m4.x) * rsqrtf(v4.x + BN_EPS) + b4.x + hres.x;
    y.y = g4.y * (acc.y - m4.y) * rsqrtf(v4.y + BN_EPS) + b4.y + hres.y;
    y.z = g4.z * (acc.z - m4.z) * rsqrtf(v4.z + BN_EPS) + b4.z + hres.z;
    y.w = g4.w * (acc.w - m4.w) * rsqrtf(v4.w + BN_EPS) + b4.w + hres.w;
    ((float4*)hout)[tid] = y;
}

// ---------------- fused pool (per-graph segment mean) + MLP head; no atomics ----------------
__global__ __launch_bounds__(256) void k_pool_head(
    const float* __restrict__ h, const int* __restrict__ start,
    const float* __restrict__ W1, const float* __restrict__ b1,
    const float* __restrict__ W2, const float* __restrict__ b2,
    float* __restrict__ out)
{
    __shared__ float sums[16][68];
    __shared__ float pl[HDIM];
    __shared__ float zl[HDIM];
    int g = blockIdx.x;
    int s0 = start[g], s1 = start[g + 1];
    int t = threadIdx.x, jq = t & 15, rp = t >> 4;
    float4 acc = make_float4(0.f, 0.f, 0.f, 0.f);
    for (int n = s0 + rp; n < s1; n += 16) {
        float4 v = ((const float4*)h)[(size_t)n * 16 + jq];
        acc.x += v.x; acc.y += v.y; acc.z += v.z; acc.w += v.w;
    }
    *(float4*)&sums[rp][jq * 4] = acc;
    __syncthreads();
    if (t < HDIM) {
        float a = 0.f;
        #pragma unroll
        for (int r = 0; r < 16; ++r) a += sums[r][t];
        float cnt = (float)(s1 - s0);
        pl[t] = a / fmaxf(cnt, 1.0f);
    }
    __syncthreads();
    if (t < HDIM) {
        float a = b1[t];
        #pragma unroll
        for (int k = 0; k < HDIM; ++k) a += pl[k] * W1[k * HDIM + t];
        zl[t] = fmaxf(a, 0.f);
    }
    __syncthreads();
    if (t < OUT_DIM) {
        float a = b2[t];
        #pragma unroll
        for (int k = 0; k < HDIM; ++k) a += zl[k] * W2[k * OUT_DIM + t];
        out[(size_t)g * OUT_DIM + t] = a;
    }
}

// ---------------- launch ----------------
extern "C" void kernel_launch(void* const* d_in, const int* in_sizes, int n_in,
                              void* d_out, int out_size, void* d_ws, size_t ws_size,
                              hipStream_t stream) {
    const float* x     = (const float*)d_in[0];
    const float* eattr = (const float*)d_in[1];
    const int*   src   = (const int*)d_in[2];
    const int*   dst   = (const int*)d_in[3];
    const int*   batch = (const int*)d_in[4];
    const float* Wx    = (const float*)d_in[5];
    const float* bx    = (const float*)d_in[6];
    const float* We    = (const float*)d_in[7];
    const float* be    = (const float*)d_in[8];
    const float* Wroot = (const float*)d_in[9];
    const float* broot = (const float*)d_in[10];
    const float* gam   = (const float*)d_in[11];
    const float* bet   = (const float*)d_in[12];
    const float* rmean = (const float*)d_in[13];
    const float* rvar  = (const float*)d_in[14];
    const float* W1    = (const float*)d_in[15];
    const float* b1    = (const float*)d_in[16];
    const float* W2    = (const float*)d_in[17];
    const float* b2    = (const float*)d_in[18];
    float* out = (float*)d_out;

    const int N = in_sizes[0] / IN_DIM;
    const int E = in_sizes[2];
    const int G = out_size / OUT_DIM;

    char* ws = (char*)d_ws;
    size_t off = 0;
    auto alloc = [&](size_t bytes) -> void* {
        void* p = ws + off;
        off = (off + bytes + 255) & ~(size_t)255;
        return p;
    };
    float*    h0    = (float*)alloc((size_t)N * HDIM * 4);
    float*    h1    = (float*)alloc((size_t)N * HDIM * 4);
    _Float16* eaH   = (_Float16*)alloc((size_t)E * 16 * 2);
    uint4*    WeB   = (uint4*)alloc((size_t)3 * 8192 * 16);
    int*      start = (int*)alloc((size_t)(G + 1) * 4);
    // contiguous zero region: deg, agg
    char*  zbase   = ws + off;
    float* deg     = (float*)alloc((size_t)N * 4);
    float* agg     = (float*)alloc((size_t)N * HDIM * 4);
    size_t zbytes  = (size_t)((ws + off) - zbase);
    (void)ws_size; (void)n_in;

    hipMemsetAsync(zbase, 0, zbytes, stream);

    k_prep<<<(E * 8 + 255) / 256, 256, 0, stream>>>(eattr, eaH, dst, deg, E);
    k_bounds<<<1, 128, 0, stream>>>(batch, start, N, G);
    k_pack_we<<<96, 256, 0, stream>>>(We, WeB);
    k_encode<<<(N * 16 + 255) / 256, 256, 0, stream>>>(x, Wx, bx, h0, N);

    const float* hin = h0;
    float* hout = h1;
    const int edgeBlocks = (E + 63) / 64;
    for (int l = 0; l < 3; ++l) {
        k_edge<<<edgeBlocks, 256, 0, stream>>>(
            (const uint4*)eaH, WeB + (size_t)l * 8192, be + (size_t)l * 4096,
            hin, src, dst, agg, E);
        k_update<<<(N * 16 + 255) / 256, 256, 0, stream>>>(
            agg, deg, hin, Wroot + (size_t)l * 4096, broot + (size_t)l * 64,
            gam + (size_t)l * 64, bet + (size_t)l * 64, rmean + (size_t)l * 64,
            rvar + (size_t)l * 64, hout, N);
        float* tmp = hout; hout = (float*)hin; hin = tmp;
    }
    k_pool_head<<<G, 256, 0, stream>>>(hin, start, W1, b1, W2, b2, out);
}